// Round 6
// baseline (341.156 us; speedup 1.0000x reference)
//
#include <hip/hip_runtime.h>
#include <math.h>

#define T 2048
#define HID 2048
#define NH 32
#define NKV 4
#define HD 128
#define QKV_DIM 5120   // (NH + 2*NKV) * HD
#define OD 4096        // NH * HD
// SCALE * log2(e): scores go straight to log2 domain
#define C2LOG 0.12751743f
#define MFIX 6.0f      // fixed softmax exponent shift (cancels in O/l)

typedef _Float16 half8 __attribute__((ext_vector_type(8)));
typedef _Float16 half4v __attribute__((ext_vector_type(4)));
typedef float floatx4 __attribute__((ext_vector_type(4)));
typedef float floatx16 __attribute__((ext_vector_type(16)));
typedef unsigned uint4v __attribute__((ext_vector_type(4)));

// async global->LDS, 16B per lane; LDS dest is wave-uniform base + lane*16
#define GLD16(gp, lp) __builtin_amdgcn_global_load_lds( \
    (const __attribute__((address_space(1))) void*)(gp), \
    (__attribute__((address_space(3))) void*)(lp), 16, 0, 0)

// pack two f32 -> one u32 of 2x f16 (v_cvt_pkrtz_f16_f32)
__device__ __forceinline__ unsigned pk_u32(float a, float b) {
    auto h = __builtin_amdgcn_cvt_pkrtz(a, b);   // __fp16 ext_vector(2)
    return __builtin_bit_cast(unsigned, h);
}
// v_permlane32_swap_b32: a := [a_lo | b_lo], b := [a_hi | b_hi]
__device__ __forceinline__ void plswap(unsigned &a, unsigned &b) {
    asm("v_permlane32_swap_b32 %0, %1" : "+v"(a), "+v"(b));
}

// ---------------- fused fp32 -> fp16 conversion (hidden, w_qkv, w_o) -------
__global__ __launch_bounds__(256)
void cvt_all(const float* __restrict__ h, const float* __restrict__ wq,
             const float* __restrict__ wo, _Float16* __restrict__ out) {
    size_t i = ((size_t)blockIdx.x * 256 + threadIdx.x) * 4;
    const float* src;
    size_t off;
    if (i < (size_t)T * HID)                        { src = h;  off = i; }
    else if (i < (size_t)T * HID + (size_t)QKV_DIM * HID)
                                                    { src = wq; off = i - (size_t)T * HID; }
    else                                            { src = wo; off = i - (size_t)T * HID - (size_t)QKV_DIM * HID; }
    float4 v = *(const float4*)(src + off);
    half4v o = { (_Float16)v.x, (_Float16)v.y, (_Float16)v.z, (_Float16)v.w };
    *(half4v*)(out + i) = o;
}

// -------- split-K GEMM (NT), fp16 partial out, 2-phase pipelined -----------
__global__ __launch_bounds__(256)
void gemm_sk_h(const _Float16* __restrict__ A, const _Float16* __restrict__ B,
               _Float16* __restrict__ p0, _Float16* __restrict__ p1,
               int M, int N, int K, int KS) {
    __shared__ __align__(16) _Float16 Asm[8192];  // [2 bufs][128][32]
    __shared__ __align__(16) _Float16 Bsm[8192];
    int tid = threadIdx.x;
    int wave = tid >> 6, lane = tid & 63;
    int quad = lane >> 4, l16 = lane & 15;
    int m0 = blockIdx.y * 128, n0 = blockIdx.x * 128;
    int koff = blockIdx.z * KS;
    _Float16* C = blockIdx.z ? p1 : p0;
    int wm = (wave >> 1) * 64, wn = (wave & 1) * 64;
    const _Float16* Ag = A + (size_t)(m0 + (tid >> 2)) * K + koff + (tid & 3) * 8;
    const _Float16* Bg = B + (size_t)(n0 + (tid >> 2)) * K + koff + (tid & 3) * 8;
    size_t row64 = (size_t)64 * K;
    int wofs = wave * 512;
    floatx4 acc[4][4] = {};
    int nt = KS >> 5;   // 32-wide K panels
    GLD16(Ag, Asm + wofs);
    GLD16(Ag + row64, Asm + 2048 + wofs);
    GLD16(Bg, Bsm + wofs);
    GLD16(Bg + row64, Bsm + 2048 + wofs);
    for (int t = 0; t < nt; t++) {
        int cur = t & 1;
        if (t + 1 < nt) {
            const _Float16* Agp = Ag + (size_t)(t + 1) * 32;
            const _Float16* Bgp = Bg + (size_t)(t + 1) * 32;
            int nb = (cur ^ 1) * 4096 + wofs;
            GLD16(Agp, Asm + nb);
            GLD16(Agp + row64, Asm + nb + 2048);
            GLD16(Bgp, Bsm + nb);
            GLD16(Bgp + row64, Bsm + nb + 2048);
            asm volatile("s_waitcnt vmcnt(4)" ::: "memory");  // panel t done
        } else {
            asm volatile("s_waitcnt vmcnt(0)" ::: "memory");
        }
        __builtin_amdgcn_s_barrier();        // panel t visible to all waves
        __builtin_amdgcn_sched_barrier(0);
        int pb = cur * 4096;
        half8 af[4], bf[4];
        #pragma unroll
        for (int i = 0; i < 4; i++)
            af[i] = *(const half8*)&Asm[pb + (wm + i * 16 + l16) * 32 + quad * 8];
        #pragma unroll
        for (int j = 0; j < 4; j++)
            bf[j] = *(const half8*)&Bsm[pb + (wn + j * 16 + l16) * 32 + quad * 8];
        #pragma unroll
        for (int i = 0; i < 4; i++)
            #pragma unroll
            for (int j = 0; j < 4; j++)
                acc[i][j] = __builtin_amdgcn_mfma_f32_16x16x32_f16(af[i], bf[j], acc[i][j], 0, 0, 0);
        __builtin_amdgcn_s_barrier();        // all waves done reading panel t
    }
    #pragma unroll
    for (int i = 0; i < 4; i++) {
        int row = m0 + wm + i * 16 + quad * 4;
        #pragma unroll
        for (int j = 0; j < 4; j++) {
            int col = n0 + wn + j * 16 + l16;
            #pragma unroll
            for (int r = 0; r < 4; r++)
                C[(size_t)(row + r) * N + col] = (_Float16)acc[i][j][r];
        }
    }
}

// -------- split-K GEMM (NT), fp16 partials x4, 2-phase pipelined -----------
__global__ __launch_bounds__(256)
void gemm_sk_f(const _Float16* __restrict__ A, const _Float16* __restrict__ B,
               _Float16* __restrict__ p0, _Float16* __restrict__ p1,
               _Float16* __restrict__ p2, _Float16* __restrict__ p3,
               int M, int N, int K, int KS) {
    __shared__ __align__(16) _Float16 Asm[8192];
    __shared__ __align__(16) _Float16 Bsm[8192];
    int tid = threadIdx.x;
    int wave = tid >> 6, lane = tid & 63;
    int quad = lane >> 4, l16 = lane & 15;
    int m0 = blockIdx.y * 128, n0 = blockIdx.x * 128;
    int bz = blockIdx.z;
    int koff = bz * KS;
    _Float16* C = (bz == 0) ? p0 : (bz == 1) ? p1 : (bz == 2) ? p2 : p3;
    int wm = (wave >> 1) * 64, wn = (wave & 1) * 64;
    const _Float16* Ag = A + (size_t)(m0 + (tid >> 2)) * K + koff + (tid & 3) * 8;
    const _Float16* Bg = B + (size_t)(n0 + (tid >> 2)) * K + koff + (tid & 3) * 8;
    size_t row64 = (size_t)64 * K;
    int wofs = wave * 512;
    floatx4 acc[4][4] = {};
    int nt = KS >> 5;
    GLD16(Ag, Asm + wofs);
    GLD16(Ag + row64, Asm + 2048 + wofs);
    GLD16(Bg, Bsm + wofs);
    GLD16(Bg + row64, Bsm + 2048 + wofs);
    for (int t = 0; t < nt; t++) {
        int cur = t & 1;
        if (t + 1 < nt) {
            const _Float16* Agp = Ag + (size_t)(t + 1) * 32;
            const _Float16* Bgp = Bg + (size_t)(t + 1) * 32;
            int nb = (cur ^ 1) * 4096 + wofs;
            GLD16(Agp, Asm + nb);
            GLD16(Agp + row64, Asm + nb + 2048);
            GLD16(Bgp, Bsm + nb);
            GLD16(Bgp + row64, Bsm + nb + 2048);
            asm volatile("s_waitcnt vmcnt(4)" ::: "memory");
        } else {
            asm volatile("s_waitcnt vmcnt(0)" ::: "memory");
        }
        __builtin_amdgcn_s_barrier();
        __builtin_amdgcn_sched_barrier(0);
        int pb = cur * 4096;
        half8 af[4], bf[4];
        #pragma unroll
        for (int i = 0; i < 4; i++)
            af[i] = *(const half8*)&Asm[pb + (wm + i * 16 + l16) * 32 + quad * 8];
        #pragma unroll
        for (int j = 0; j < 4; j++)
            bf[j] = *(const half8*)&Bsm[pb + (wn + j * 16 + l16) * 32 + quad * 8];
        #pragma unroll
        for (int i = 0; i < 4; i++)
            #pragma unroll
            for (int j = 0; j < 4; j++)
                acc[i][j] = __builtin_amdgcn_mfma_f32_16x16x32_f16(af[i], bf[j], acc[i][j], 0, 0, 0);
        __builtin_amdgcn_s_barrier();
    }
    #pragma unroll
    for (int i = 0; i < 4; i++) {
        int row = m0 + wm + i * 16 + quad * 4;
        #pragma unroll
        for (int j = 0; j < 4; j++) {
            int col = n0 + wn + j * 16 + l16;
            #pragma unroll
            for (int r = 0; r < 4; r++)
                C[(size_t)(row + r) * N + col] = (_Float16)acc[i][j][r];
        }
    }
}

// ---------------- reduce 4 fp16 partials -> fp32 out ------------------------
__global__ __launch_bounds__(256)
void reduce4(const _Float16* __restrict__ p0, const _Float16* __restrict__ p1,
             const _Float16* __restrict__ p2, const _Float16* __restrict__ p3,
             float* __restrict__ out) {
    size_t i = ((size_t)blockIdx.x * 256 + threadIdx.x) * 4;
    half4v a = *(const half4v*)(p0 + i);
    half4v b = *(const half4v*)(p1 + i);
    half4v c = *(const half4v*)(p2 + i);
    half4v d = *(const half4v*)(p3 + i);
    float4 o = { (float)a.x + (float)b.x + (float)c.x + (float)d.x,
                 (float)a.y + (float)b.y + (float)c.y + (float)d.y,
                 (float)a.z + (float)b.z + (float)c.z + (float)d.z,
                 (float)a.w + (float)b.w + (float)c.w + (float)d.w };
    *(float4*)(out + i) = o;
}

// ---------------- RMSNorm + RoPE + reorder (sums 2 fp16 partials) ----------
__global__ __launch_bounds__(256)
void qkv_post(const _Float16* __restrict__ qp0, const _Float16* __restrict__ qp1,
              const int* __restrict__ positions,
              const float* __restrict__ qw, const float* __restrict__ kw,
              _Float16* __restrict__ Qb, _Float16* __restrict__ Kb,
              _Float16* __restrict__ Vt) {
    int t = blockIdx.x;
    int wave = threadIdx.x >> 6, lane = threadIdx.x & 63;
    float pos = (float)positions[t];
    float f = exp2f(-(float)lane * (19.9315685693241741f / 64.0f));
    float ang = pos * f;
    float s = sinf(ang), c = cosf(ang);
    const _Float16* r0 = qp0 + (size_t)t * QKV_DIM;
    const _Float16* r1 = qp1 + (size_t)t * QKV_DIM;
    for (int hh = wave; hh < NH + 2 * NKV; hh += 4) {
        float x1 = (float)r0[hh * HD + lane] + (float)r1[hh * HD + lane];
        float x2 = (float)r0[hh * HD + lane + 64] + (float)r1[hh * HD + lane + 64];
        if (hh < NH + NKV) {
            float ss = x1 * x1 + x2 * x2;
            for (int o = 1; o < 64; o <<= 1) ss += __shfl_xor(ss, o);
            float inv = rsqrtf(ss * (1.0f / HD) + 1e-6f);
            const float* w = (hh < NH) ? qw : kw;
            x1 = x1 * inv * w[lane];
            x2 = x2 * inv * w[lane + 64];
            float y1 = x1 * c - x2 * s;
            float y2 = x2 * c + x1 * s;
            _Float16* dst;
            if (hh < NH) dst = Qb + ((size_t)hh * T + t) * HD;
            else         dst = Kb + ((size_t)(hh - NH) * T + t) * HD;
            dst[lane]      = (_Float16)y1;
            dst[lane + 64] = (_Float16)y2;
        } else {
            int hk = hh - NH - NKV;
            Vt[((size_t)hk * HD + lane) * T + t]      = (_Float16)x1;
            Vt[((size_t)hk * HD + lane + 64) * T + t] = (_Float16)x2;
        }
    }
}

// ---------------- Flash attention: 512 blocks x 128 q-rows, 32x32 MFMA -----
// Swapped QK^T (mfma(K,Q)): D[kv][q] with q = lane&31 -> each lane owns the
// full P row of ITS q. Softmax is lane-local (no per-tile shuffle reduce);
// P goes straight to PV A-fragments in-register via cvt_pkrtz +
// v_permlane32_swap (T12) -- the P LDS round-trip (32 stores + lgkm drain +
// 4 reads per wave-tile, the r0..r4-invariant serial chain) is eliminated.
__global__ __launch_bounds__(256, 2)
void attn(const _Float16* __restrict__ Qb, const _Float16* __restrict__ Kb,
          const _Float16* __restrict__ Vt, _Float16* __restrict__ Ob) {
    __shared__ __align__(16) _Float16 Ksm[8192];    // [64][128] colblk ^ (row&7)
    __shared__ __align__(16) _Float16 Vsm[8192];    // [128][64] colblk ^ (row&7)
    int b = blockIdx.x;
    int halfg = b >> 8;             // 0: long half (j=8..15), 1: short (j=0..7)
    int idx = b & 255;
    int h = idx & 31;
    int qi = idx >> 5;              // 0..7
    int j = halfg ? qi : 15 - qi;   // q-block index, 128 rows each
    int hk = h >> 3;
    int tid = threadIdx.x, wave = tid >> 6, lane = tid & 63;
    int l31 = lane & 31, hi = lane >> 5;
    int wq0 = j * 128 + wave * 32;
    int qa = wq0 + l31;             // this lane's own q row

    // Q fragment (B-operand): lane holds Q[q=l31][k = kb*16 + hi*8 + 0..7]
    half8 qf[8];
    {
        const _Float16* qp = Qb + ((size_t)h * T + qa) * HD + hi * 8;
        #pragma unroll
        for (int kb = 0; kb < 8; kb++)
            qf[kb] = *(const half8*)(qp + kb * 16);
    }
    floatx16 o_acc[4] = {};   // [dblock]: O[q=crow(r,hi)][d=db*32+l31]
    float lsum = 0.0f;

    int krow = tid >> 4;
    const _Float16* Kg = Kb + ((size_t)hk * T + krow) * HD + ((tid & 15) ^ (krow & 7)) * 8;
    int vrow = tid >> 3;
    const _Float16* Vg = Vt + ((size_t)hk * HD + vrow) * T + ((tid & 7) ^ (vrow & 7)) * 8;
    _Float16* KsmW = Ksm + wave * 512;
    _Float16* VsmW = Vsm + wave * 512;

    int ntiles = 2 * j + 2;
    for (int it = 0; it < ntiles; it++) {
        int kv0 = it * 64;
        __syncthreads();
        {
            const _Float16* kg = Kg + (size_t)kv0 * HD;
            const _Float16* vg = Vg + kv0;
            #pragma unroll
            for (int c = 0; c < 4; c++) {
                GLD16(kg + (size_t)c * (16 * HD), KsmW + c * 2048);
                GLD16(vg + (size_t)c * (32 * T), VsmW + c * 2048);
            }
        }
        __syncthreads();

        bool needmask = (it >= ntiles - 2);
        half8 af[4];                 // PV A-frags: 4 kv-chunks of 16
        #pragma unroll
        for (int s = 0; s < 2; s++) {           // kv slabs of 32
            int row = s * 32 + l31;
            int rs = row & 7;
            floatx16 sc = {};
            #pragma unroll
            for (int kb = 0; kb < 8; kb++) {    // HD in 16-k steps
                half8 kf = *(const half8*)&Ksm[row * 128 + (((kb * 2 + hi) ^ rs)) * 8];
                sc = __builtin_amdgcn_mfma_f32_32x32x16_f16(kf, qf[kb], sc, 0, 0, 0);
            }
            // P = exp2(s*c - MFIX); lane's q = l31; kv = kv0+s*32+crow(r,hi)
            float pe[16];
            #pragma unroll
            for (int r = 0; r < 16; r++) {
                float p = __builtin_amdgcn_exp2f(
                    __builtin_fmaf(sc[r], C2LOG, -MFIX));
                if (needmask) {
                    int kv = kv0 + s * 32 + (r & 3) + 8 * (r >> 2) + 4 * hi;
                    p = (kv <= qa) ? p : 0.0f;
                }
                lsum += p;
                pe[r] = p;
            }
            // assemble A-frags: frag = {swapA.lo, swapB.lo, swapA.hi, swapB.hi}
            #pragma unroll
            for (int c = 0; c < 2; c++) {       // 16-kv chunks within slab
                int rb = c * 8;
                unsigned x0 = pk_u32(pe[rb + 0], pe[rb + 1]);
                unsigned y0 = pk_u32(pe[rb + 4], pe[rb + 5]);
                plswap(x0, y0);                 // x0=word0, y0=word2
                unsigned x1 = pk_u32(pe[rb + 2], pe[rb + 3]);
                unsigned y1 = pk_u32(pe[rb + 6], pe[rb + 7]);
                plswap(x1, y1);                 // x1=word1, y1=word3
                uint4v w = { x0, x1, y0, y1 };
                af[s * 2 + c] = __builtin_bit_cast(half8, w);
            }
        }
        // PV: O[q][d] += P[q][kv] * V[kv][d];  B-frag = Vsm[d][kv-chunk]
        #pragma unroll
        for (int db = 0; db < 4; db++) {
            int row = db * 32 + l31;
            int rs = row & 7;
            #pragma unroll
            for (int c = 0; c < 4; c++) {
                half8 vf = *(const half8*)&Vsm[row * 64 + (((c * 2 + hi) ^ rs)) * 8];
                o_acc[db] = __builtin_amdgcn_mfma_f32_32x32x16_f16(af[c], vf, o_acc[db], 0, 0, 0);
            }
        }
    }

    // lane&31 and lane^32 hold the two kv-halves of the same q
    lsum += __shfl_xor(lsum, 32);
    float linv = 1.0f / lsum;
    float li[16];
    #pragma unroll
    for (int r = 0; r < 16; r++) {
        int rq = (r & 3) + 8 * (r >> 2) + 4 * hi;
        li[r] = __shfl(linv, rq);
    }
    #pragma unroll
    for (int db = 0; db < 4; db++) {
        int col = h * HD + db * 32 + l31;
        #pragma unroll
        for (int r = 0; r < 16; r++) {
            int rq = (r & 3) + 8 * (r >> 2) + 4 * hi;
            Ob[(size_t)(wq0 + rq) * OD + col] = (_Float16)(o_acc[db][r] * li[r]);
        }
    }
}

extern "C" void kernel_launch(void* const* d_in, const int* in_sizes, int n_in,
                              void* d_out, int out_size, void* d_ws, size_t ws_size,
                              hipStream_t stream) {
    const int*   positions = (const int*)d_in[0];
    const float* hidden    = (const float*)d_in[1];
    const float* w_qkv     = (const float*)d_in[2];
    const float* w_o       = (const float*)d_in[3];
    const float* q_norm_w  = (const float*)d_in[4];
    const float* k_norm_w  = (const float*)d_in[5];
    float* out = (float*)d_out;

    const size_t MiB = 1048576;
    char* ws = (char*)d_ws;
    // live ranges (MiB): hb[0,8) wqkvb[8,28) wob[28,44) qkvp0[44,64) qkvp1[64,84)
    // Qb[84,100) Kb[100,102) Vt[102,104) Ob[104,120)
    // out fp16 partials (8.4 MiB ea) reuse dead regions: [0,9) [9,18) [44,53) [53,62)
    _Float16* hb    = (_Float16*)(ws);
    _Float16* wqkvb = (_Float16*)(ws + 8 * MiB);
    _Float16* wob   = (_Float16*)(ws + 28 * MiB);
    _Float16* qkvp0 = (_Float16*)(ws + 44 * MiB);
    _Float16* qkvp1 = (_Float16*)(ws + 64 * MiB);
    _Float16* Qb    = (_Float16*)(ws + 84 * MiB);
    _Float16* Kb    = (_Float16*)(ws + 100 * MiB);
    _Float16* Vt    = (_Float16*)(ws + 102 * MiB);
    _Float16* Ob    = (_Float16*)(ws + 104 * MiB);
    _Float16* op0   = (_Float16*)(ws);
    _Float16* op1   = (_Float16*)(ws + 9 * MiB);
    _Float16* op2   = (_Float16*)(ws + 44 * MiB);
    _Float16* op3   = (_Float16*)(ws + 53 * MiB);

    cvt_all<<<22528, 256, 0, stream>>>(hidden, w_qkv, w_o, hb);

    // qkv partial GEMMs: split-K=2 over K=2048
    gemm_sk_h<<<dim3(QKV_DIM / 128, T / 128, 2), 256, 0, stream>>>(
        hb, wqkvb, qkvp0, qkvp1, T, QKV_DIM, HID, HID / 2);

    qkv_post<<<T, 256, 0, stream>>>(qkvp0, qkvp1, positions, q_norm_w, k_norm_w, Qb, Kb, Vt);

    attn<<<512, 256, 0, stream>>>(Qb, Kb, Vt, Ob);

    // out projection: split-K=4 over K=4096
    gemm_sk_f<<<dim3(HID / 128, T / 128, 4), 256, 0, stream>>>(
        Ob, wob, op0, op1, op2, op3, T, HID, OD, OD / 4);
    reduce4<<<T * HID / 1024, 256, 0, stream>>>(op0, op1, op2, op3, out);
}

// Round 9
// 330.487 us; speedup vs baseline: 1.0323x; 1.0323x over previous
//
#include <hip/hip_runtime.h>
#include <math.h>

#define T 2048
#define HID 2048
#define NH 32
#define NKV 4
#define HD 128
#define QKV_DIM 5120   // (NH + 2*NKV) * HD
#define OD 4096        // NH * HD
#define VOFF 4608      // (NH+NKV)*HD — V column offset in qkv
// SCALE * log2(e): scores go straight to log2 domain
#define C2LOG 0.12751743f
#define MFIX 6.0f      // fixed softmax exponent shift (cancels in O/l)

typedef _Float16 half8 __attribute__((ext_vector_type(8)));
typedef _Float16 half4v __attribute__((ext_vector_type(4)));
typedef float floatx4 __attribute__((ext_vector_type(4)));
typedef float floatx16 __attribute__((ext_vector_type(16)));
typedef unsigned uint4v __attribute__((ext_vector_type(4)));

// async global->LDS, 16B per lane; LDS dest is wave-uniform base + lane*16
#define GLD16(gp, lp) __builtin_amdgcn_global_load_lds( \
    (const __attribute__((address_space(1))) void*)(gp), \
    (__attribute__((address_space(3))) void*)(lp), 16, 0, 0)

// pack two f32 -> one u32 of 2x f16 (v_cvt_pkrtz_f16_f32)
__device__ __forceinline__ unsigned pk_u32(float a, float b) {
    auto h = __builtin_amdgcn_cvt_pkrtz(a, b);   // __fp16 ext_vector(2)
    return __builtin_bit_cast(unsigned, h);
}
// v_permlane32_swap_b32: a := [a_lo | b_lo], b := [a_hi | b_hi]
__device__ __forceinline__ void plswap(unsigned &a, unsigned &b) {
    asm("v_permlane32_swap_b32 %0, %1" : "+v"(a), "+v"(b));
}

// ---------------- fused fp32 -> fp16 conversion (hidden, w_qkv, w_o) -------
__global__ __launch_bounds__(256)
void cvt_all(const float* __restrict__ h, const float* __restrict__ wq,
             const float* __restrict__ wo, _Float16* __restrict__ out) {
    size_t i = ((size_t)blockIdx.x * 256 + threadIdx.x) * 4;
    const float* src;
    size_t off;
    if (i < (size_t)T * HID)                        { src = h;  off = i; }
    else if (i < (size_t)T * HID + (size_t)QKV_DIM * HID)
                                                    { src = wq; off = i - (size_t)T * HID; }
    else                                            { src = wo; off = i - (size_t)T * HID - (size_t)QKV_DIM * HID; }
    float4 v = *(const float4*)(src + off);
    half4v o = { (_Float16)v.x, (_Float16)v.y, (_Float16)v.z, (_Float16)v.w };
    *(half4v*)(out + i) = o;
}

// -------- split-K GEMM (NT), fp16 partials x2, 2-phase pipelined -----------
// Used for BOTH the qkv projection and the out projection (z-dim = 2).
__global__ __launch_bounds__(256)
void gemm_sk_h(const _Float16* __restrict__ A, const _Float16* __restrict__ B,
               _Float16* __restrict__ p0, _Float16* __restrict__ p1,
               int M, int N, int K, int KS) {
    __shared__ __align__(16) _Float16 Asm[8192];  // [2 bufs][128][32]
    __shared__ __align__(16) _Float16 Bsm[8192];
    int tid = threadIdx.x;
    int wave = tid >> 6, lane = tid & 63;
    int quad = lane >> 4, l16 = lane & 15;
    int m0 = blockIdx.y * 128, n0 = blockIdx.x * 128;
    int koff = blockIdx.z * KS;
    _Float16* C = blockIdx.z ? p1 : p0;
    int wm = (wave >> 1) * 64, wn = (wave & 1) * 64;
    const _Float16* Ag = A + (size_t)(m0 + (tid >> 2)) * K + koff + (tid & 3) * 8;
    const _Float16* Bg = B + (size_t)(n0 + (tid >> 2)) * K + koff + (tid & 3) * 8;
    size_t row64 = (size_t)64 * K;
    int wofs = wave * 512;
    floatx4 acc[4][4] = {};
    int nt = KS >> 5;   // 32-wide K panels
    GLD16(Ag, Asm + wofs);
    GLD16(Ag + row64, Asm + 2048 + wofs);
    GLD16(Bg, Bsm + wofs);
    GLD16(Bg + row64, Bsm + 2048 + wofs);
    for (int t = 0; t < nt; t++) {
        int cur = t & 1;
        if (t + 1 < nt) {
            const _Float16* Agp = Ag + (size_t)(t + 1) * 32;
            const _Float16* Bgp = Bg + (size_t)(t + 1) * 32;
            int nb = (cur ^ 1) * 4096 + wofs;
            GLD16(Agp, Asm + nb);
            GLD16(Agp + row64, Asm + nb + 2048);
            GLD16(Bgp, Bsm + nb);
            GLD16(Bgp + row64, Bsm + nb + 2048);
            asm volatile("s_waitcnt vmcnt(4)" ::: "memory");  // panel t done
        } else {
            asm volatile("s_waitcnt vmcnt(0)" ::: "memory");
        }
        __builtin_amdgcn_s_barrier();        // panel t visible to all waves
        __builtin_amdgcn_sched_barrier(0);
        int pb = cur * 4096;
        half8 af[4], bf[4];
        #pragma unroll
        for (int i = 0; i < 4; i++)
            af[i] = *(const half8*)&Asm[pb + (wm + i * 16 + l16) * 32 + quad * 8];
        #pragma unroll
        for (int j = 0; j < 4; j++)
            bf[j] = *(const half8*)&Bsm[pb + (wn + j * 16 + l16) * 32 + quad * 8];
        #pragma unroll
        for (int i = 0; i < 4; i++)
            #pragma unroll
            for (int j = 0; j < 4; j++)
                acc[i][j] = __builtin_amdgcn_mfma_f32_16x16x32_f16(af[i], bf[j], acc[i][j], 0, 0, 0);
        __builtin_amdgcn_s_barrier();        // all waves done reading panel t
    }
    #pragma unroll
    for (int i = 0; i < 4; i++) {
        int row = m0 + wm + i * 16 + quad * 4;
        #pragma unroll
        for (int j = 0; j < 4; j++) {
            int col = n0 + wn + j * 16 + l16;
            #pragma unroll
            for (int r = 0; r < 4; r++)
                C[(size_t)(row + r) * N + col] = (_Float16)acc[i][j][r];
        }
    }
}

// ---------------- reduce 2 fp16 partials -> fp32 out ------------------------
__global__ __launch_bounds__(256)
void reduce2(const _Float16* __restrict__ p0, const _Float16* __restrict__ p1,
             float* __restrict__ out) {
    size_t i = ((size_t)blockIdx.x * 256 + threadIdx.x) * 4;
    half4v a = *(const half4v*)(p0 + i);
    half4v b = *(const half4v*)(p1 + i);
    float4 o = { (float)a.x + (float)b.x, (float)a.y + (float)b.y,
                 (float)a.z + (float)b.z, (float)a.w + (float)b.w };
    *(float4*)(out + i) = o;
}

// ---------------- RMSNorm + RoPE (Q/K only; V handled by v_trans) ----------
__global__ __launch_bounds__(256)
void qkv_post(const _Float16* __restrict__ qp0, const _Float16* __restrict__ qp1,
              const int* __restrict__ positions,
              const float* __restrict__ qw, const float* __restrict__ kw,
              _Float16* __restrict__ Qb, _Float16* __restrict__ Kb) {
    int t = blockIdx.x;
    int wave = threadIdx.x >> 6, lane = threadIdx.x & 63;
    float pos = (float)positions[t];
    float f = exp2f(-(float)lane * (19.9315685693241741f / 64.0f));
    float ang = pos * f;
    float s = sinf(ang), c = cosf(ang);
    const _Float16* r0 = qp0 + (size_t)t * QKV_DIM;
    const _Float16* r1 = qp1 + (size_t)t * QKV_DIM;
    for (int hh = wave; hh < NH + NKV; hh += 4) {
        float x1 = (float)r0[hh * HD + lane] + (float)r1[hh * HD + lane];
        float x2 = (float)r0[hh * HD + lane + 64] + (float)r1[hh * HD + lane + 64];
        float ss = x1 * x1 + x2 * x2;
        for (int o = 1; o < 64; o <<= 1) ss += __shfl_xor(ss, o);
        float inv = rsqrtf(ss * (1.0f / HD) + 1e-6f);
        const float* w = (hh < NH) ? qw : kw;
        x1 = x1 * inv * w[lane];
        x2 = x2 * inv * w[lane + 64];
        float y1 = x1 * c - x2 * s;
        float y2 = x2 * c + x1 * s;
        _Float16* dst;
        if (hh < NH) dst = Qb + ((size_t)hh * T + t) * HD;
        else         dst = Kb + ((size_t)(hh - NH) * T + t) * HD;
        dst[lane]      = (_Float16)y1;
        dst[lane + 64] = (_Float16)y2;
    }
}

// ---------------- V: sum partials + transpose [T][512] -> [512][T] ---------
// 64x64 tiles via LDS; reads and writes both fully coalesced (128B bursts),
// replacing qkv_post's 2B x 4KB-stride scatter (64 line-touches per store).
__global__ __launch_bounds__(256)
void v_trans(const _Float16* __restrict__ qp0, const _Float16* __restrict__ qp1,
             _Float16* __restrict__ Vt) {
    __shared__ _Float16 Ls[64][72];   // +8 pad breaks read-phase bank alias
    int tz = blockIdx.x & 31, dz = blockIdx.x >> 5;   // 32 t-tiles x 8 d-tiles
    int tid = threadIdx.x;
    int rr = tid >> 3, c8 = (tid & 7) * 8;
    #pragma unroll
    for (int it = 0; it < 2; it++) {
        int row = it * 32 + rr;   // t-local
        size_t src = (size_t)(tz * 64 + row) * QKV_DIM + VOFF + dz * 64 + c8;
        half8 a = *(const half8*)(qp0 + src);
        half8 b = *(const half8*)(qp1 + src);
        half8 sv;
        #pragma unroll
        for (int e = 0; e < 8; e++) sv[e] = (_Float16)((float)a[e] + (float)b[e]);
        *(half8*)&Ls[row][c8] = sv;
    }
    __syncthreads();
    #pragma unroll
    for (int it = 0; it < 2; it++) {
        int d = it * 32 + rr;     // d-local
        half8 o;
        #pragma unroll
        for (int e = 0; e < 8; e++) o[e] = Ls[c8 + e][d];
        *(half8*)(Vt + (size_t)(dz * 64 + d) * T + tz * 64 + c8) = o;
    }
}

// ---------------- Flash attention: 512 blocks x 128 q-rows, 32x32 MFMA -----
// (r6 version, verified passing at 73.5us.) Swapped QK^T (mfma(K,Q)): each
// lane owns the full P row of ITS q; softmax lane-local; P -> PV A-frags
// in-register via cvt_pkrtz + permlane32_swap (no P LDS round-trip).
__global__ __launch_bounds__(256, 2)
void attn(const _Float16* __restrict__ Qb, const _Float16* __restrict__ Kb,
          const _Float16* __restrict__ Vt, _Float16* __restrict__ Ob) {
    __shared__ __align__(16) _Float16 Ksm[8192];    // [64][128] colblk ^ (row&7)
    __shared__ __align__(16) _Float16 Vsm[8192];    // [128][64] colblk ^ (row&7)
    int b = blockIdx.x;
    int halfg = b >> 8;             // 0: long half (j=8..15), 1: short (j=0..7)
    int idx = b & 255;
    int h = idx & 31;
    int qi = idx >> 5;              // 0..7
    int j = halfg ? qi : 15 - qi;   // q-block index, 128 rows each
    int hk = h >> 3;
    int tid = threadIdx.x, wave = tid >> 6, lane = tid & 63;
    int l31 = lane & 31, hi = lane >> 5;
    int wq0 = j * 128 + wave * 32;
    int qa = wq0 + l31;             // this lane's own q row

    half8 qf[8];
    {
        const _Float16* qp = Qb + ((size_t)h * T + qa) * HD + hi * 8;
        #pragma unroll
        for (int kb = 0; kb < 8; kb++)
            qf[kb] = *(const half8*)(qp + kb * 16);
    }
    floatx16 o_acc[4] = {};   // [dblock]: O[q=crow(r,hi)][d=db*32+l31]
    float lsum = 0.0f;

    int krow = tid >> 4;
    const _Float16* Kg = Kb + ((size_t)hk * T + krow) * HD + ((tid & 15) ^ (krow & 7)) * 8;
    int vrow = tid >> 3;
    const _Float16* Vg = Vt + ((size_t)hk * HD + vrow) * T + ((tid & 7) ^ (vrow & 7)) * 8;
    _Float16* KsmW = Ksm + wave * 512;
    _Float16* VsmW = Vsm + wave * 512;

    int ntiles = 2 * j + 2;
    for (int it = 0; it < ntiles; it++) {
        int kv0 = it * 64;
        __syncthreads();
        {
            const _Float16* kg = Kg + (size_t)kv0 * HD;
            const _Float16* vg = Vg + kv0;
            #pragma unroll
            for (int c = 0; c < 4; c++) {
                GLD16(kg + (size_t)c * (16 * HD), KsmW + c * 2048);
                GLD16(vg + (size_t)c * (32 * T), VsmW + c * 2048);
            }
        }
        __syncthreads();

        bool needmask = (it >= ntiles - 2);
        half8 af[4];                 // PV A-frags: 4 kv-chunks of 16
        #pragma unroll
        for (int s = 0; s < 2; s++) {           // kv slabs of 32
            int row = s * 32 + l31;
            int rs = row & 7;
            floatx16 sc = {};
            #pragma unroll
            for (int kb = 0; kb < 8; kb++) {    // HD in 16-k steps
                half8 kf = *(const half8*)&Ksm[row * 128 + (((kb * 2 + hi) ^ rs)) * 8];
                sc = __builtin_amdgcn_mfma_f32_32x32x16_f16(kf, qf[kb], sc, 0, 0, 0);
            }
            float pe[16];
            #pragma unroll
            for (int r = 0; r < 16; r++) {
                float p = __builtin_amdgcn_exp2f(
                    __builtin_fmaf(sc[r], C2LOG, -MFIX));
                if (needmask) {
                    int kv = kv0 + s * 32 + (r & 3) + 8 * (r >> 2) + 4 * hi;
                    p = (kv <= qa) ? p : 0.0f;
                }
                lsum += p;
                pe[r] = p;
            }
            #pragma unroll
            for (int c = 0; c < 2; c++) {       // 16-kv chunks within slab
                int rb = c * 8;
                unsigned x0 = pk_u32(pe[rb + 0], pe[rb + 1]);
                unsigned y0 = pk_u32(pe[rb + 4], pe[rb + 5]);
                plswap(x0, y0);
                unsigned x1 = pk_u32(pe[rb + 2], pe[rb + 3]);
                unsigned y1 = pk_u32(pe[rb + 6], pe[rb + 7]);
                plswap(x1, y1);
                uint4v w = { x0, x1, y0, y1 };
                af[s * 2 + c] = __builtin_bit_cast(half8, w);
            }
        }
        #pragma unroll
        for (int db = 0; db < 4; db++) {
            int row = db * 32 + l31;
            int rs = row & 7;
            #pragma unroll
            for (int c = 0; c < 4; c++) {
                half8 vf = *(const half8*)&Vsm[row * 64 + (((c * 2 + hi) ^ rs)) * 8];
                o_acc[db] = __builtin_amdgcn_mfma_f32_32x32x16_f16(af[c], vf, o_acc[db], 0, 0, 0);
            }
        }
    }

    lsum += __shfl_xor(lsum, 32);
    float linv = 1.0f / lsum;
    float li[16];
    #pragma unroll
    for (int r = 0; r < 16; r++) {
        int rq = (r & 3) + 8 * (r >> 2) + 4 * hi;
        li[r] = __shfl(linv, rq);
    }
    #pragma unroll
    for (int db = 0; db < 4; db++) {
        int col = h * HD + db * 32 + l31;
        #pragma unroll
        for (int r = 0; r < 16; r++) {
            int rq = (r & 3) + 8 * (r >> 2) + 4 * hi;
            Ob[(size_t)(wq0 + rq) * OD + col] = (_Float16)(o_acc[db][r] * li[r]);
        }
    }
}

extern "C" void kernel_launch(void* const* d_in, const int* in_sizes, int n_in,
                              void* d_out, int out_size, void* d_ws, size_t ws_size,
                              hipStream_t stream) {
    const int*   positions = (const int*)d_in[0];
    const float* hidden    = (const float*)d_in[1];
    const float* w_qkv     = (const float*)d_in[2];
    const float* w_o       = (const float*)d_in[3];
    const float* q_norm_w  = (const float*)d_in[4];
    const float* k_norm_w  = (const float*)d_in[5];
    float* out = (float*)d_out;

    const size_t MiB = 1048576;
    char* ws = (char*)d_ws;
    // live ranges (MiB): hb[0,8) wqkvb[8,28) wob[28,44) qkvp0[44,64) qkvp1[64,84)
    // Qb[84,100) Kb[100,102) Vt[102,104) Ob[104,120)
    // out fp16 partials (8.4 MiB ea) reuse dead regions: [0,9) [9,18)
    _Float16* hb    = (_Float16*)(ws);
    _Float16* wqkvb = (_Float16*)(ws + 8 * MiB);
    _Float16* wob   = (_Float16*)(ws + 28 * MiB);
    _Float16* qkvp0 = (_Float16*)(ws + 44 * MiB);
    _Float16* qkvp1 = (_Float16*)(ws + 64 * MiB);
    _Float16* Qb    = (_Float16*)(ws + 84 * MiB);
    _Float16* Kb    = (_Float16*)(ws + 100 * MiB);
    _Float16* Vt    = (_Float16*)(ws + 102 * MiB);
    _Float16* Ob    = (_Float16*)(ws + 104 * MiB);
    _Float16* op0   = (_Float16*)(ws);
    _Float16* op1   = (_Float16*)(ws + 9 * MiB);

    cvt_all<<<22528, 256, 0, stream>>>(hidden, w_qkv, w_o, hb);

    // qkv projection: split-K=2 over K=2048
    gemm_sk_h<<<dim3(QKV_DIM / 128, T / 128, 2), 256, 0, stream>>>(
        hb, wqkvb, qkvp0, qkvp1, T, QKV_DIM, HID, HID / 2);

    qkv_post<<<T, 256, 0, stream>>>(qkvp0, qkvp1, positions, q_norm_w, k_norm_w, Qb, Kb);
    v_trans<<<256, 256, 0, stream>>>(qkvp0, qkvp1, Vt);

    attn<<<512, 256, 0, stream>>>(Qb, Kb, Vt, Ob);

    // out projection: split-K=2 over K=4096 (reuses gemm_sk_h)
    gemm_sk_h<<<dim3(HID / 128, T / 128, 2), 256, 0, stream>>>(
        Ob, wob, op0, op1, T, HID, OD, OD / 2);
    reduce2<<<T * HID / 1024, 256, 0, stream>>>(op0, op1, out);
}